// Round 4
// baseline (431.981 us; speedup 1.0000x reference)
//
#include <hip/hip_runtime.h>

#define B_   8
#define C_   256
#define H_   64
#define W2_  64
#define CO_  256
#define HW_  4096
#define NK   9
#define NSTEP 72   /* K = 9*256 = 2304, 32 per step */

typedef __attribute__((ext_vector_type(8))) short s16x8;
typedef __attribute__((ext_vector_type(4))) float f32x4;
typedef __attribute__((ext_vector_type(2))) unsigned int u32x2;

static __device__ __forceinline__ unsigned short f2bf(float f) {
    unsigned x = __float_as_uint(f);
    unsigned r = x + 0x7fffu + ((x >> 16) & 1u);   // RNE to bf16
    return (unsigned short)(r >> 16);
}

// ---------------- mask branch: depthwise3x3+relu -> pointwise1x1 -> sigmoid ----------------
__global__ __launch_bounds__(256) void mask_kernel(
    const float* __restrict__ x, const float* __restrict__ dw,
    const float* __restrict__ pw, const float* __restrict__ pb,
    float* __restrict__ mask_out)
{
    __shared__ float hdn[C_ * 64];          // hdn[c][w ^ (c&31)]  (XOR swizzle, 64KB)
    const int bid = blockIdx.x;             // b*64 + h
    const int b = bid >> 6, h = bid & 63;
    const int t = threadIdx.x;
    const int w = t & 63, cg = t >> 6;

    // depthwise: lanes over w (coalesced), each wave owns 64 channels
    for (int c = cg * 64; c < cg * 64 + 64; ++c) {
        const float* xc = x + ((size_t)(b * C_ + c)) * HW_;
        const float* km = dw + c * 9;
        float s = 0.f;
        #pragma unroll
        for (int i = 0; i < 3; ++i) {
            int hh = h + i - 1;
            if (hh >= 0 && hh < 64) {
                const float* rr = xc + hh * 64;
                float lft = (w > 0)  ? rr[w - 1] : 0.f;
                float mid = rr[w];
                float rgt = (w < 63) ? rr[w + 1] : 0.f;
                s = fmaf(km[i*3+0], lft, s);
                s = fmaf(km[i*3+1], mid, s);
                s = fmaf(km[i*3+2], rgt, s);
            }
        }
        hdn[c * 64 + (w ^ (c & 31))] = fmaxf(s, 0.f);
    }
    __syncthreads();

    // pointwise + sigmoid: thread (w, kgroup) handles up to 3 taps
    const int kk0 = cg * 3;
    for (int kk = kk0; kk < kk0 + 3; ++kk) {
        if (kk >= NK) break;
        float acc = pb[kk];
        const float* pwk = pw + kk * C_;
        for (int c = 0; c < C_; ++c)
            acc = fmaf(pwk[c], hdn[c * 64 + (w ^ (c & 31))], acc);
        mask_out[((size_t)(b * NK + kk)) * HW_ + h * 64 + w] = 1.f / (1.f + __expf(-acc));
    }
}

// ---------------- weight prep: conv_w [o][c][kt] f32 -> bf16 [s][o][32k], K = kt*256 + c ----------------
__global__ __launch_bounds__(256) void wprep_kernel(
    const float* __restrict__ cw, unsigned short* __restrict__ wp)
{
    const int i = blockIdx.x * 256 + threadIdx.x;   // i = (s*256 + o)*32 + kp,  total 72*256*32
    const int kp = i & 31;
    const int so = i >> 5;
    const int o = so & 255;
    const int s = so >> 8;
    const int K = s * 32 + kp;          // K = kt*256 + c
    const int kt = K >> 8, c = K & 255;
    wp[i] = f2bf(cw[(o * C_ + c) * 9 + kt]);
}

// ---------------- main fused kernel: sample+mask (bf16) -> MFMA GEMM ----------------
__global__ __launch_bounds__(512) void main_kernel(
    const float* __restrict__ x, const float* __restrict__ offset,
    const float* __restrict__ mask, const unsigned short* __restrict__ wprep,
    const float* __restrict__ cb, float* __restrict__ out)
{
    // S-tile LDS: rows = 64 pixels, 32 bf16 (64B) padded to 80B stride, double buffered
    __shared__ short slds[2][64 * 40];

    const int bid = blockIdx.x;
    const int b = bid & 7;              // same-b blocks share an XCD's L2 (x[b] = 4MB)
    const int row = bid >> 3;           // image row = pixel tile
    const int t = threadIdx.x;

    // staging role
    const int pl = t & 63;              // pixel (= w coordinate)
    const int csub = (t >> 6) << 2;     // c offset within 32-chunk (0,4,...,28)
    // mfma role
    const int lane = t & 63, wid = t >> 6;
    const int wm = wid >> 1, wpn = wid & 1;     // wave tile: 64o x 32p
    const int l15 = lane & 15, g = lane >> 4;

    f32x4 acc[4][2];
    #pragma unroll
    for (int m = 0; m < 4; ++m)
        #pragma unroll
        for (int n = 0; n < 2; ++n)
            acc[m][n] = (f32x4)0.f;

    int cached_tap = -1;
    int i00, i01, i10, i11;
    float w00, w01, w10, w11;

    auto ensure = [&](int kt) {
        cached_tap = kt;
        const int kd = kt / 3;
        const int dyk = kd - 1, dxk = kt - kd * 3 - 1;
        const size_t ob = ((size_t)(b * 18 + 2 * kt)) * HW_ + row * 64 + pl;
        const float ody = offset[ob];           // (dy,dx) per tap
        const float odx = offset[ob + HW_];
        const float py = (float)(row + dyk) + ody;
        const float px = (float)(pl + dxk) + odx;
        const float y0f = floorf(py), x0f = floorf(px);
        const float wy = py - y0f, wx = px - x0f;
        const int y0 = (int)y0f, x0 = (int)x0f;
        const float mm = mask[((size_t)(b * NK + kt)) * HW_ + row * 64 + pl];
        const float omy = 1.f - wy, omx = 1.f - wx;

        int iy, ix, iyc, ixc; bool v;
        iy = y0; ix = x0;
        v = (iy >= 0) & (iy < 64) & (ix >= 0) & (ix < 64);
        iyc = iy < 0 ? 0 : (iy > 63 ? 63 : iy); ixc = ix < 0 ? 0 : (ix > 63 ? 63 : ix);
        i00 = iyc * 64 + ixc; w00 = v ? omy * omx * mm : 0.f;
        iy = y0; ix = x0 + 1;
        v = (iy >= 0) & (iy < 64) & (ix >= 0) & (ix < 64);
        iyc = iy < 0 ? 0 : (iy > 63 ? 63 : iy); ixc = ix < 0 ? 0 : (ix > 63 ? 63 : ix);
        i01 = iyc * 64 + ixc; w01 = v ? omy * wx * mm : 0.f;
        iy = y0 + 1; ix = x0;
        v = (iy >= 0) & (iy < 64) & (ix >= 0) & (ix < 64);
        iyc = iy < 0 ? 0 : (iy > 63 ? 63 : iy); ixc = ix < 0 ? 0 : (ix > 63 ? 63 : ix);
        i10 = iyc * 64 + ixc; w10 = v ? wy * omx * mm : 0.f;
        iy = y0 + 1; ix = x0 + 1;
        v = (iy >= 0) & (iy < 64) & (ix >= 0) & (ix < 64);
        iyc = iy < 0 ? 0 : (iy > 63 ? 63 : iy); ixc = ix < 0 ? 0 : (ix > 63 ? 63 : ix);
        i11 = iyc * 64 + ixc; w11 = v ? wy * wx * mm : 0.f;
    };

    auto stage = [&](int buf, int s) {
        const int kt = s >> 3;
        if (kt != cached_tap) ensure(kt);
        const int cc = ((s & 7) << 5) + csub;
        const float* xb = x + ((size_t)(b * C_ + cc)) * HW_;
        unsigned short u[4];
        #pragma unroll
        for (int j = 0; j < 4; ++j) {
            const float* bp = xb + j * HW_;
            float v = fmaf(w00, bp[i00], fmaf(w01, bp[i01], fmaf(w10, bp[i10], w11 * bp[i11])));
            u[j] = f2bf(v);
        }
        u32x2 pk;
        pk.x = (unsigned)u[0] | ((unsigned)u[1] << 16);
        pk.y = (unsigned)u[2] | ((unsigned)u[3] << 16);
        *reinterpret_cast<u32x2*>(&slds[buf][pl * 40 + csub]) = pk;   // 8B, aligned
    };

    auto compute = [&](int buf, int s) {
        const unsigned short* wpbase = wprep + (size_t)s * (CO_ * 32);
        s16x8 a[4];
        #pragma unroll
        for (int m = 0; m < 4; ++m) {
            const int o = wm * 64 + m * 16 + l15;
            a[m] = *reinterpret_cast<const s16x8*>(wpbase + o * 32 + g * 8);  // A[o][k], k=g*8+j
        }
        #pragma unroll
        for (int n = 0; n < 2; ++n) {
            const int pr = wpn * 32 + n * 16 + l15;
            const s16x8 bb = *reinterpret_cast<const s16x8*>(&slds[buf][pr * 40 + g * 8]);  // B[k][p]
            #pragma unroll
            for (int m = 0; m < 4; ++m)
                acc[m][n] = __builtin_amdgcn_mfma_f32_16x16x32_bf16(a[m], bb, acc[m][n], 0, 0, 0);
        }
    };

    stage(0, 0);
    __syncthreads();
    for (int s = 0; s < NSTEP; ++s) {
        if (s + 1 < NSTEP) stage((s + 1) & 1, s + 1);
        compute(s & 1, s);
        __syncthreads();
    }

    // epilogue: D col = lane&15 (pixel), row = g*4 + r (o)
    #pragma unroll
    for (int m = 0; m < 4; ++m) {
        #pragma unroll
        for (int n = 0; n < 2; ++n) {
            const int o0 = wm * 64 + m * 16 + g * 4;
            const int pc = row * 64 + wpn * 32 + n * 16 + l15;
            #pragma unroll
            for (int r = 0; r < 4; ++r) {
                const int o = o0 + r;
                out[((size_t)(b * CO_ + o)) * HW_ + pc] = acc[m][n][r] + cb[o];
            }
        }
    }
}

extern "C" void kernel_launch(void* const* d_in, const int* in_sizes, int n_in,
                              void* d_out, int out_size, void* d_ws, size_t ws_size,
                              hipStream_t stream) {
    const float* x      = (const float*)d_in[0];
    const float* offset = (const float*)d_in[1];
    const float* dw     = (const float*)d_in[2];
    const float* pw     = (const float*)d_in[3];
    const float* pb     = (const float*)d_in[4];
    const float* cw     = (const float*)d_in[5];
    const float* cb     = (const float*)d_in[6];
    float* out = (float*)d_out;

    float* mask_ws = (float*)d_ws;                                    // B*9*4096 f32 = 1.18MB
    unsigned short* wprep = (unsigned short*)((char*)d_ws + (size_t)B_ * NK * HW_ * sizeof(float));
                                                                      // 72*256*32 bf16 = 1.18MB

    mask_kernel<<<B_ * 64, 256, 0, stream>>>(x, dw, pw, pb, mask_ws);
    wprep_kernel<<<(NSTEP * CO_ * 32) / 256, 256, 0, stream>>>(cw, wprep);
    main_kernel<<<512, 512, 0, stream>>>(x, offset, mask_ws, wprep, cb, out);
}

// Round 7
// 313.945 us; speedup vs baseline: 1.3760x; 1.3760x over previous
//
#include <hip/hip_runtime.h>

#define B_   8
#define C_   256
#define CO_  256
#define HW_  4096
#define NK   9
#define NSTEP 72   /* K = 9*256 = 2304, 32 per step */

typedef __attribute__((ext_vector_type(8))) short s16x8;
typedef __attribute__((ext_vector_type(8))) unsigned short u16x8;
typedef __attribute__((ext_vector_type(4))) float f32x4;
typedef __attribute__((ext_vector_type(4))) int i32x4;
typedef __attribute__((ext_vector_type(2))) unsigned int u32x2;

static __device__ __forceinline__ unsigned short f2bf(float f) {
    unsigned x = __float_as_uint(f);
    unsigned r = x + 0x7fffu + ((x >> 16) & 1u);   // RNE to bf16
    return (unsigned short)(r >> 16);
}
static __device__ __forceinline__ float bfu2f(unsigned short u) {
    return __uint_as_float(((unsigned)u) << 16);
}

// ---------------- NCHW f32 -> NHWC bf16 transpose ----------------
__global__ __launch_bounds__(256) void tr_kernel(
    const float* __restrict__ x, unsigned short* __restrict__ xT)
{
    __shared__ unsigned lds[64][33];
    const int bid = blockIdx.x;            // b*64 + h
    const int b = bid >> 6, h = bid & 63;
    const int t = threadIdx.x;
    const int w = t & 63, cr = t >> 6;     // read role
    const int px = t >> 2, seg = t & 3;    // write role
    for (int chunk = 0; chunk < 4; ++chunk) {
        const float* base = x + (((size_t)(b * C_ + chunk * 64 + cr * 16)) * 64 + h) * 64 + w;
        #pragma unroll
        for (int i2 = 0; i2 < 8; ++i2) {
            float f0 = base[(2 * i2) * HW_];
            float f1 = base[(2 * i2 + 1) * HW_];
            lds[w][cr * 8 + i2] = (unsigned)f2bf(f0) | ((unsigned)f2bf(f1) << 16);
        }
        __syncthreads();
        unsigned short* dst = xT + (((size_t)(b * 64 + h)) * 64 + px) * C_ + chunk * 64 + seg * 16;
        i32x4 v0 = { (int)lds[px][seg*8+0], (int)lds[px][seg*8+1], (int)lds[px][seg*8+2], (int)lds[px][seg*8+3] };
        i32x4 v1 = { (int)lds[px][seg*8+4], (int)lds[px][seg*8+5], (int)lds[px][seg*8+6], (int)lds[px][seg*8+7] };
        *reinterpret_cast<i32x4*>(dst) = v0;
        *reinterpret_cast<i32x4*>(dst + 8) = v1;
        __syncthreads();
    }
}

// ---------------- mask branch (NHWC bf16 x): dw3x3+relu -> pw1x1 -> sigmoid ----------------
__global__ __launch_bounds__(256) void mask2_kernel(
    const unsigned short* __restrict__ xT, const float* __restrict__ dw,
    const float* __restrict__ pw, const float* __restrict__ pb,
    float* __restrict__ mask_out)
{
    __shared__ float ldw[9 * 264 + 8];   // skewed: idx = tap*264 + c + (c>>5)
    __shared__ float lpw[9 * 264 + 8];   // skewed: idx = k*264 + c + (c>>5)
    const int bid = blockIdx.x;          // b*64 + h
    const int b = bid >> 6, h = bid & 63;
    const int t = threadIdx.x;
    for (int i = t; i < 2304; i += 256) {
        int c = i / 9, tap = i - c * 9;          // dw flat = c*9+tap
        ldw[tap * 264 + c + (c >> 5)] = dw[i];
        int k = i >> 8, c2 = i & 255;            // pw flat = k*256+c
        lpw[k * 264 + c2 + (c2 >> 5)] = pw[i];
    }
    __syncthreads();
    const int px = t >> 2, seg = t & 3;
    float hdn[64];
    #pragma unroll
    for (int i = 0; i < 64; ++i) hdn[i] = 0.f;
    const unsigned short* xb = xT + (size_t)b * (64 * 64 * 256);
    #pragma unroll
    for (int tap = 0; tap < 9; ++tap) {
        const int dy = tap / 3 - 1, dx = tap % 3 - 1;
        const int y = h + dy, xx = px + dx;
        if (y >= 0 && y < 64 && xx >= 0 && xx < 64) {
            const unsigned short* src = xb + (((size_t)(y * 64 + xx)) << 8);
            #pragma unroll
            for (int i = 0; i < 8; ++i) {
                const int c0 = (i * 4 + seg) * 8;
                const int sk = c0 >> 5;
                u16x8 v = *reinterpret_cast<const u16x8*>(src + c0);
                #pragma unroll
                for (int j = 0; j < 8; ++j)
                    hdn[i * 8 + j] = fmaf(ldw[tap * 264 + c0 + j + sk], bfu2f(v[j]), hdn[i * 8 + j]);
            }
        }
    }
    float part[9];
    #pragma unroll
    for (int k = 0; k < 9; ++k) part[k] = 0.f;
    #pragma unroll
    for (int i = 0; i < 8; ++i) {
        const int c0 = (i * 4 + seg) * 8;
        const int sk = c0 >> 5;
        #pragma unroll
        for (int j = 0; j < 8; ++j) {
            float hv = fmaxf(hdn[i * 8 + j], 0.f);
            #pragma unroll
            for (int k = 0; k < 9; ++k)
                part[k] = fmaf(lpw[k * 264 + c0 + j + sk], hv, part[k]);
        }
    }
    #pragma unroll
    for (int k = 0; k < 9; ++k) {
        part[k] += __shfl_xor(part[k], 1);
        part[k] += __shfl_xor(part[k], 2);
    }
    if (seg == 0) {
        #pragma unroll
        for (int k = 0; k < 9; ++k) {
            float a = part[k] + pb[k];
            mask_out[((size_t)(b * NK + k)) * HW_ + h * 64 + px] = 1.f / (1.f + __expf(-a));
        }
    }
}

// ---------------- weight prep: conv_w [o][c][kt] f32 -> bf16 [s][o][32k], K = kt*256 + c ----------------
__global__ __launch_bounds__(256) void wprep_kernel(
    const float* __restrict__ cw, unsigned short* __restrict__ wp)
{
    const int i = blockIdx.x * 256 + threadIdx.x;
    const int kp = i & 31;
    const int so = i >> 5;
    const int o = so & 255;
    const int s = so >> 8;
    const int K = s * 32 + kp;
    const int kt = K >> 8, c = K & 255;
    wp[i] = f2bf(cw[(o * C_ + c) * 9 + kt]);
}

// ---------------- main fused kernel v4: round-4-PROVEN skeleton, xT gather source ----------------
// Identical to the round-4 clean main_kernel except `stage` loads 4 channels as
// 4 x 8B bf16 vectors from NHWC xT instead of 16 scalar f32 loads from NCHW x.
__global__ __launch_bounds__(512) void main4_kernel(
    const unsigned short* __restrict__ xT, const float* __restrict__ offset,
    const float* __restrict__ mask, const unsigned short* __restrict__ wprep,
    const float* __restrict__ cb, float* __restrict__ out)
{
    __shared__ short slds[2][64 * 40];   // [buf][px][32k] bf16, 80B row stride (round-4 proven)

    const int bid = blockIdx.x;
    const int b = bid & 7;
    const int row = bid >> 3;
    const int t = threadIdx.x;
    const int pl = t & 63;
    const int csub = (t >> 6) << 2;
    const int lane = t & 63, wid = t >> 6;
    const int wm = wid >> 1, wpn = wid & 1;
    const int l15 = lane & 15, g = lane >> 4;

    const unsigned short* xTb = xT + (size_t)b * (HW_ * C_);

    f32x4 acc[4][2];
    #pragma unroll
    for (int m = 0; m < 4; ++m)
        #pragma unroll
        for (int n = 0; n < 2; ++n)
            acc[m][n] = (f32x4)0.f;

    int cached_tap = -1;
    int i00, i01, i10, i11;
    float w00, w01, w10, w11;

    auto ensure = [&](int kt) {
        cached_tap = kt;
        const int kd = kt / 3;
        const int dyk = kd - 1, dxk = kt - kd * 3 - 1;
        const size_t ob = ((size_t)(b * 18 + 2 * kt)) * HW_ + row * 64 + pl;
        const float ody = offset[ob];
        const float odx = offset[ob + HW_];
        const float py = (float)(row + dyk) + ody;
        const float px = (float)(pl + dxk) + odx;
        const float y0f = floorf(py), x0f = floorf(px);
        const float wy = py - y0f, wx = px - x0f;
        const int y0 = (int)y0f, x0 = (int)x0f;
        const float mm = mask[((size_t)(b * NK + kt)) * HW_ + row * 64 + pl];
        const float omy = 1.f - wy, omx = 1.f - wx;
        int iy, ix, iyc, ixc; bool v;
        iy = y0; ix = x0;
        v = (iy >= 0) & (iy < 64) & (ix >= 0) & (ix < 64);
        iyc = iy < 0 ? 0 : (iy > 63 ? 63 : iy); ixc = ix < 0 ? 0 : (ix > 63 ? 63 : ix);
        i00 = iyc * 64 + ixc; w00 = v ? omy * omx * mm : 0.f;
        iy = y0; ix = x0 + 1;
        v = (iy >= 0) & (iy < 64) & (ix >= 0) & (ix < 64);
        iyc = iy < 0 ? 0 : (iy > 63 ? 63 : iy); ixc = ix < 0 ? 0 : (ix > 63 ? 63 : ix);
        i01 = iyc * 64 + ixc; w01 = v ? omy * wx * mm : 0.f;
        iy = y0 + 1; ix = x0;
        v = (iy >= 0) & (iy < 64) & (ix >= 0) & (ix < 64);
        iyc = iy < 0 ? 0 : (iy > 63 ? 63 : iy); ixc = ix < 0 ? 0 : (ix > 63 ? 63 : ix);
        i10 = iyc * 64 + ixc; w10 = v ? wy * omx * mm : 0.f;
        iy = y0 + 1; ix = x0 + 1;
        v = (iy >= 0) & (iy < 64) & (ix >= 0) & (ix < 64);
        iyc = iy < 0 ? 0 : (iy > 63 ? 63 : iy); ixc = ix < 0 ? 0 : (ix > 63 ? 63 : ix);
        i11 = iyc * 64 + ixc; w11 = v ? wy * wx * mm : 0.f;
    };

    auto stage = [&](int buf, int s) {
        const int kt = s >> 3;
        if (kt != cached_tap) ensure(kt);
        const int cc = ((s & 7) << 5) + csub;                 // 4-channel base within K-chunk
        const unsigned short* xb = xTb + cc;
        // 4 corners x 4 consecutive bf16 channels = 8B vector loads
        u32x2 q00 = *reinterpret_cast<const u32x2*>(xb + (size_t)i00 * C_);
        u32x2 q01 = *reinterpret_cast<const u32x2*>(xb + (size_t)i01 * C_);
        u32x2 q10 = *reinterpret_cast<const u32x2*>(xb + (size_t)i10 * C_);
        u32x2 q11 = *reinterpret_cast<const u32x2*>(xb + (size_t)i11 * C_);
        unsigned short u[4];
        #pragma unroll
        for (int j = 0; j < 4; ++j) {
            const int word = j >> 1, sh = (j & 1) << 4;
            float v = fmaf(w00, bfu2f((unsigned short)(q00[word] >> sh)),
                      fmaf(w01, bfu2f((unsigned short)(q01[word] >> sh)),
                      fmaf(w10, bfu2f((unsigned short)(q10[word] >> sh)),
                           w11 * bfu2f((unsigned short)(q11[word] >> sh)))));
            u[j] = f2bf(v);
        }
        u32x2 pk;
        pk.x = (unsigned)u[0] | ((unsigned)u[1] << 16);
        pk.y = (unsigned)u[2] | ((unsigned)u[3] << 16);
        *reinterpret_cast<u32x2*>(&slds[buf][pl * 40 + csub]) = pk;   // 8B, aligned (round-4 layout)
    };

    auto compute = [&](int buf, int s) {
        const unsigned short* wpbase = wprep + (size_t)s * (CO_ * 32);
        s16x8 a[4];
        #pragma unroll
        for (int m = 0; m < 4; ++m) {
            const int o = wm * 64 + m * 16 + l15;
            a[m] = *reinterpret_cast<const s16x8*>(wpbase + o * 32 + g * 8);
        }
        #pragma unroll
        for (int n = 0; n < 2; ++n) {
            const int pr = wpn * 32 + n * 16 + l15;
            const s16x8 bb = *reinterpret_cast<const s16x8*>(&slds[buf][pr * 40 + g * 8]);
            #pragma unroll
            for (int m = 0; m < 4; ++m)
                acc[m][n] = __builtin_amdgcn_mfma_f32_16x16x32_bf16(a[m], bb, acc[m][n], 0, 0, 0);
        }
    };

    stage(0, 0);
    __syncthreads();
    for (int s = 0; s < NSTEP; ++s) {
        if (s + 1 < NSTEP) stage((s + 1) & 1, s + 1);
        compute(s & 1, s);
        __syncthreads();
    }

    // epilogue: D col = lane&15 (pixel), row = g*4 + r (o)
    #pragma unroll
    for (int m = 0; m < 4; ++m) {
        #pragma unroll
        for (int n = 0; n < 2; ++n) {
            const int o0 = wm * 64 + m * 16 + g * 4;
            const int pc = row * 64 + wpn * 32 + n * 16 + l15;
            #pragma unroll
            for (int r = 0; r < 4; ++r) {
                const int o = o0 + r;
                out[((size_t)(b * CO_ + o)) * HW_ + pc] = acc[m][n][r] + cb[o];
            }
        }
    }
}

// ================= fallback path (round-4 verified kernels, used if ws too small) =================
__global__ __launch_bounds__(256) void mask_kernel(
    const float* __restrict__ x, const float* __restrict__ dw,
    const float* __restrict__ pw, const float* __restrict__ pb,
    float* __restrict__ mask_out)
{
    __shared__ float hdn[C_ * 64];
    const int bid = blockIdx.x;
    const int b = bid >> 6, h = bid & 63;
    const int t = threadIdx.x;
    const int w = t & 63, cg = t >> 6;
    for (int c = cg * 64; c < cg * 64 + 64; ++c) {
        const float* xc = x + ((size_t)(b * C_ + c)) * HW_;
        const float* km = dw + c * 9;
        float s = 0.f;
        #pragma unroll
        for (int i = 0; i < 3; ++i) {
            int hh = h + i - 1;
            if (hh >= 0 && hh < 64) {
                const float* rr = xc + hh * 64;
                float lft = (w > 0)  ? rr[w - 1] : 0.f;
                float mid = rr[w];
                float rgt = (w < 63) ? rr[w + 1] : 0.f;
                s = fmaf(km[i*3+0], lft, s);
                s = fmaf(km[i*3+1], mid, s);
                s = fmaf(km[i*3+2], rgt, s);
            }
        }
        hdn[c * 64 + (w ^ (c & 31))] = fmaxf(s, 0.f);
    }
    __syncthreads();
    const int kk0 = cg * 3;
    for (int kk = kk0; kk < kk0 + 3; ++kk) {
        if (kk >= NK) break;
        float acc = pb[kk];
        const float* pwk = pw + kk * C_;
        for (int c = 0; c < C_; ++c)
            acc = fmaf(pwk[c], hdn[c * 64 + (w ^ (c & 31))], acc);
        mask_out[((size_t)(b * NK + kk)) * HW_ + h * 64 + w] = 1.f / (1.f + __expf(-acc));
    }
}

__global__ __launch_bounds__(512) void main_kernel(
    const float* __restrict__ x, const float* __restrict__ offset,
    const float* __restrict__ mask, const unsigned short* __restrict__ wprep,
    const float* __restrict__ cb, float* __restrict__ out)
{
    __shared__ short slds[2][64 * 40];
    const int bid = blockIdx.x;
    const int b = bid & 7;
    const int row = bid >> 3;
    const int t = threadIdx.x;
    const int pl = t & 63;
    const int csub = (t >> 6) << 2;
    const int lane = t & 63, wid = t >> 6;
    const int wm = wid >> 1, wpn = wid & 1;
    const int l15 = lane & 15, g = lane >> 4;
    f32x4 acc[4][2];
    #pragma unroll
    for (int m = 0; m < 4; ++m)
        #pragma unroll
        for (int n = 0; n < 2; ++n)
            acc[m][n] = (f32x4)0.f;
    int cached_tap = -1;
    int i00, i01, i10, i11;
    float w00, w01, w10, w11;
    auto ensure = [&](int kt) {
        cached_tap = kt;
        const int kd = kt / 3;
        const int dyk = kd - 1, dxk = kt - kd * 3 - 1;
        const size_t ob = ((size_t)(b * 18 + 2 * kt)) * HW_ + row * 64 + pl;
        const float ody = offset[ob];
        const float odx = offset[ob + HW_];
        const float py = (float)(row + dyk) + ody;
        const float px = (float)(pl + dxk) + odx;
        const float y0f = floorf(py), x0f = floorf(px);
        const float wy = py - y0f, wx = px - x0f;
        const int y0 = (int)y0f, x0 = (int)x0f;
        const float mm = mask[((size_t)(b * NK + kt)) * HW_ + row * 64 + pl];
        const float omy = 1.f - wy, omx = 1.f - wx;
        int iy, ix, iyc, ixc; bool v;
        iy = y0; ix = x0;
        v = (iy >= 0) & (iy < 64) & (ix >= 0) & (ix < 64);
        iyc = iy < 0 ? 0 : (iy > 63 ? 63 : iy); ixc = ix < 0 ? 0 : (ix > 63 ? 63 : ix);
        i00 = iyc * 64 + ixc; w00 = v ? omy * omx * mm : 0.f;
        iy = y0; ix = x0 + 1;
        v = (iy >= 0) & (iy < 64) & (ix >= 0) & (ix < 64);
        iyc = iy < 0 ? 0 : (iy > 63 ? 63 : iy); ixc = ix < 0 ? 0 : (ix > 63 ? 63 : ix);
        i01 = iyc * 64 + ixc; w01 = v ? omy * wx * mm : 0.f;
        iy = y0 + 1; ix = x0;
        v = (iy >= 0) & (iy < 64) & (ix >= 0) & (ix < 64);
        iyc = iy < 0 ? 0 : (iy > 63 ? 63 : iy); ixc = ix < 0 ? 0 : (ix > 63 ? 63 : ix);
        i10 = iyc * 64 + ixc; w10 = v ? wy * omx * mm : 0.f;
        iy = y0 + 1; ix = x0 + 1;
        v = (iy >= 0) & (iy < 64) & (ix >= 0) & (ix < 64);
        iyc = iy < 0 ? 0 : (iy > 63 ? 63 : iy); ixc = ix < 0 ? 0 : (ix > 63 ? 63 : ix);
        i11 = iyc * 64 + ixc; w11 = v ? wy * wx * mm : 0.f;
    };
    auto stage = [&](int buf, int s) {
        const int kt = s >> 3;
        if (kt != cached_tap) ensure(kt);
        const int cc = ((s & 7) << 5) + csub;
        const float* xb = x + ((size_t)(b * C_ + cc)) * HW_;
        unsigned short u[4];
        #pragma unroll
        for (int j = 0; j < 4; ++j) {
            const float* bp = xb + j * HW_;
            float v = fmaf(w00, bp[i00], fmaf(w01, bp[i01], fmaf(w10, bp[i10], w11 * bp[i11])));
            u[j] = f2bf(v);
        }
        u32x2 pk;
        pk.x = (unsigned)u[0] | ((unsigned)u[1] << 16);
        pk.y = (unsigned)u[2] | ((unsigned)u[3] << 16);
        *reinterpret_cast<u32x2*>(&slds[buf][pl * 40 + csub]) = pk;
    };
    auto compute = [&](int buf, int s) {
        const unsigned short* wpbase = wprep + (size_t)s * (CO_ * 32);
        s16x8 a[4];
        #pragma unroll
        for (int m = 0; m < 4; ++m) {
            const int o = wm * 64 + m * 16 + l15;
            a[m] = *reinterpret_cast<const s16x8*>(wpbase + o * 32 + g * 8);
        }
        #pragma unroll
        for (int n = 0; n < 2; ++n) {
            const int pr = wpn * 32 + n * 16 + l15;
            const s16x8 bb = *reinterpret_cast<const s16x8*>(&slds[buf][pr * 40 + g * 8]);
            #pragma unroll
            for (int m = 0; m < 4; ++m)
                acc[m][n] = __builtin_amdgcn_mfma_f32_16x16x32_bf16(a[m], bb, acc[m][n], 0, 0, 0);
        }
    };
    stage(0, 0);
    __syncthreads();
    for (int s = 0; s < NSTEP; ++s) {
        if (s + 1 < NSTEP) stage((s + 1) & 1, s + 1);
        compute(s & 1, s);
        __syncthreads();
    }
    #pragma unroll
    for (int m = 0; m < 4; ++m) {
        #pragma unroll
        for (int n = 0; n < 2; ++n) {
            const int o0 = wm * 64 + m * 16 + g * 4;
            const int pc = row * 64 + wpn * 32 + n * 16 + l15;
            #pragma unroll
            for (int r = 0; r < 4; ++r) {
                const int o = o0 + r;
                out[((size_t)(b * CO_ + o)) * HW_ + pc] = acc[m][n][r] + cb[o];
            }
        }
    }
}

extern "C" void kernel_launch(void* const* d_in, const int* in_sizes, int n_in,
                              void* d_out, int out_size, void* d_ws, size_t ws_size,
                              hipStream_t stream) {
    const float* x      = (const float*)d_in[0];
    const float* offset = (const float*)d_in[1];
    const float* dw     = (const float*)d_in[2];
    const float* pw     = (const float*)d_in[3];
    const float* pb     = (const float*)d_in[4];
    const float* cw     = (const float*)d_in[5];
    const float* cb     = (const float*)d_in[6];
    float* out = (float*)d_out;

    const size_t XT_BYTES   = (size_t)B_ * HW_ * C_ * 2;          // 16 MB
    const size_t MASK_BYTES = (size_t)B_ * NK * HW_ * 4;          // 1.18 MB
    const size_t WP_BYTES   = (size_t)NSTEP * CO_ * 32 * 2;       // 1.18 MB

    if (ws_size >= XT_BYTES + MASK_BYTES + WP_BYTES) {
        unsigned short* xT = (unsigned short*)d_ws;
        float* mask_ws = (float*)((char*)d_ws + XT_BYTES);
        unsigned short* wprep = (unsigned short*)((char*)d_ws + XT_BYTES + MASK_BYTES);
        tr_kernel<<<B_ * 64, 256, 0, stream>>>(x, xT);
        mask2_kernel<<<B_ * 64, 256, 0, stream>>>(xT, dw, pw, pb, mask_ws);
        wprep_kernel<<<(NSTEP * CO_ * 32) / 256, 256, 0, stream>>>(cw, wprep);
        main4_kernel<<<512, 512, 0, stream>>>(xT, offset, mask_ws, wprep, cb, out);
    } else {
        float* mask_ws = (float*)d_ws;
        unsigned short* wprep = (unsigned short*)((char*)d_ws + MASK_BYTES);
        mask_kernel<<<B_ * 64, 256, 0, stream>>>(x, dw, pw, pb, mask_ws);
        wprep_kernel<<<(NSTEP * CO_ * 32) / 256, 256, 0, stream>>>(cw, wprep);
        main_kernel<<<512, 512, 0, stream>>>(x, offset, mask_ws, wprep, cb, out);
    }
}

// Round 8
// 229.725 us; speedup vs baseline: 1.8804x; 1.3666x over previous
//
#include <hip/hip_runtime.h>

#define B_   8
#define C_   256
#define CO_  256
#define HW_  4096
#define NK   9
#define NSTEP 72   /* K = 9*256 = 2304, 32 per step */

typedef __attribute__((ext_vector_type(8))) short s16x8;
typedef __attribute__((ext_vector_type(8))) unsigned short u16x8;
typedef __attribute__((ext_vector_type(4))) float f32x4;
typedef __attribute__((ext_vector_type(4))) int i32x4;
typedef __attribute__((ext_vector_type(2))) unsigned int u32x2;

static __device__ __forceinline__ unsigned short f2bf(float f) {
    unsigned x = __float_as_uint(f);
    unsigned r = x + 0x7fffu + ((x >> 16) & 1u);   // RNE to bf16
    return (unsigned short)(r >> 16);
}
static __device__ __forceinline__ float bfu2f(unsigned short u) {
    return __uint_as_float(((unsigned)u) << 16);
}

// ---------------- NCHW f32 -> NHWC bf16 transpose ----------------
__global__ __launch_bounds__(256) void tr_kernel(
    const float* __restrict__ x, unsigned short* __restrict__ xT)
{
    __shared__ unsigned lds[64][33];
    const int bid = blockIdx.x;            // b*64 + h
    const int b = bid >> 6, h = bid & 63;
    const int t = threadIdx.x;
    const int w = t & 63, cr = t >> 6;     // read role
    const int px = t >> 2, seg = t & 3;    // write role
    for (int chunk = 0; chunk < 4; ++chunk) {
        const float* base = x + (((size_t)(b * C_ + chunk * 64 + cr * 16)) * 64 + h) * 64 + w;
        #pragma unroll
        for (int i2 = 0; i2 < 8; ++i2) {
            float f0 = base[(2 * i2) * HW_];
            float f1 = base[(2 * i2 + 1) * HW_];
            lds[w][cr * 8 + i2] = (unsigned)f2bf(f0) | ((unsigned)f2bf(f1) << 16);
        }
        __syncthreads();
        unsigned short* dst = xT + (((size_t)(b * 64 + h)) * 64 + px) * C_ + chunk * 64 + seg * 16;
        i32x4 v0 = { (int)lds[px][seg*8+0], (int)lds[px][seg*8+1], (int)lds[px][seg*8+2], (int)lds[px][seg*8+3] };
        i32x4 v1 = { (int)lds[px][seg*8+4], (int)lds[px][seg*8+5], (int)lds[px][seg*8+6], (int)lds[px][seg*8+7] };
        *reinterpret_cast<i32x4*>(dst) = v0;
        *reinterpret_cast<i32x4*>(dst + 8) = v1;
        __syncthreads();
    }
}

// ---------------- mask branch (NHWC bf16 x): dw3x3+relu -> pw1x1 -> sigmoid ----------------
// 512 threads: px = t>>3 (64 pixels), sub = t&7 (32 channels each). 8-lane shfl reduce.
__global__ __launch_bounds__(512) void mask2_kernel(
    const unsigned short* __restrict__ xT, const float* __restrict__ dw,
    const float* __restrict__ pw, const float* __restrict__ pb,
    float* __restrict__ mask_out)
{
    __shared__ float ldw[9 * 264 + 8];   // skewed: idx = tap*264 + c + (c>>5)
    __shared__ float lpw[9 * 264 + 8];   // skewed: idx = k*264 + c + (c>>5)
    const int bid = blockIdx.x;          // b*64 + h
    const int b = bid >> 6, h = bid & 63;
    const int t = threadIdx.x;
    for (int i = t; i < 2304; i += 512) {
        int c = i / 9, tap = i - c * 9;          // dw flat = c*9+tap
        ldw[tap * 264 + c + (c >> 5)] = dw[i];
        int k = i >> 8, c2 = i & 255;            // pw flat = k*256+c
        lpw[k * 264 + c2 + (c2 >> 5)] = pw[i];
    }
    __syncthreads();
    const int px = t >> 3, sub = t & 7;          // 32 channels: c = sub*32 + [0,32)
    float hdn[32];
    #pragma unroll
    for (int i = 0; i < 32; ++i) hdn[i] = 0.f;
    const unsigned short* xb = xT + (size_t)b * (64 * 64 * 256);
    #pragma unroll
    for (int tap = 0; tap < 9; ++tap) {
        const int dy = tap / 3 - 1, dx = tap % 3 - 1;
        const int y = h + dy, xx = px + dx;
        if (y >= 0 && y < 64 && xx >= 0 && xx < 64) {
            const unsigned short* src = xb + (((size_t)(y * 64 + xx)) << 8) + sub * 32;
            #pragma unroll
            for (int i = 0; i < 4; ++i) {
                const int c0 = sub * 32 + i * 8;
                const int sk = c0 >> 5;
                u16x8 v = *reinterpret_cast<const u16x8*>(src + i * 8);
                #pragma unroll
                for (int j = 0; j < 8; ++j)
                    hdn[i * 8 + j] = fmaf(ldw[tap * 264 + c0 + j + sk], bfu2f(v[j]), hdn[i * 8 + j]);
            }
        }
    }
    float part[9];
    #pragma unroll
    for (int k = 0; k < 9; ++k) part[k] = 0.f;
    #pragma unroll
    for (int i = 0; i < 4; ++i) {
        const int c0 = sub * 32 + i * 8;
        const int sk = c0 >> 5;
        #pragma unroll
        for (int j = 0; j < 8; ++j) {
            float hv = fmaxf(hdn[i * 8 + j], 0.f);
            #pragma unroll
            for (int k = 0; k < 9; ++k)
                part[k] = fmaf(lpw[k * 264 + c0 + j + sk], hv, part[k]);
        }
    }
    #pragma unroll
    for (int k = 0; k < 9; ++k) {
        part[k] += __shfl_xor(part[k], 1);
        part[k] += __shfl_xor(part[k], 2);
        part[k] += __shfl_xor(part[k], 4);
    }
    if (sub == 0) {
        #pragma unroll
        for (int k = 0; k < 9; ++k) {
            float a = part[k] + pb[k];
            mask_out[((size_t)(b * NK + k)) * HW_ + h * 64 + px] = 1.f / (1.f + __expf(-a));
        }
    }
}

// ---------------- weight prep: conv_w [o][c][kt] f32 -> bf16 [s][o][32k], K = kt*256 + c ----------------
__global__ __launch_bounds__(256) void wprep_kernel(
    const float* __restrict__ cw, unsigned short* __restrict__ wp)
{
    const int i = blockIdx.x * 256 + threadIdx.x;
    const int kp = i & 31;
    const int so = i >> 5;
    const int o = so & 255;
    const int s = so >> 8;
    const int K = s * 32 + kp;
    const int kt = K >> 8, c = K & 255;
    wp[i] = f2bf(cw[(o * C_ + c) * 9 + kt]);
}

// ---------------- main fused kernel v5: coalesced NHWC gather (64B/corner/pixel) ----------------
// Identical to round-7-proven main4 except the staging role map: pl = t>>3, cs = (t&7)*4
// so the 8 lanes sharing a pixel read one contiguous 64B chunk per bilinear corner.
__global__ __launch_bounds__(512) void main5_kernel(
    const unsigned short* __restrict__ xT, const float* __restrict__ offset,
    const float* __restrict__ mask, const unsigned short* __restrict__ wprep,
    const float* __restrict__ cb, float* __restrict__ out)
{
    __shared__ short slds[2][64 * 40];   // [buf][px][32k] bf16, 80B row stride (proven)

    const int bid = blockIdx.x;
    const int b = bid & 7;
    const int row = bid >> 3;
    const int t = threadIdx.x;
    // staging role: 8 threads per pixel, 4 channels each
    const int pl = t >> 3;
    const int cs = (t & 7) << 2;
    // mfma role (unchanged)
    const int lane = t & 63, wid = t >> 6;
    const int wm = wid >> 1, wpn = wid & 1;
    const int l15 = lane & 15, g = lane >> 4;

    const unsigned short* xTb = xT + (size_t)b * (HW_ * C_);

    f32x4 acc[4][2];
    #pragma unroll
    for (int m = 0; m < 4; ++m)
        #pragma unroll
        for (int n = 0; n < 2; ++n)
            acc[m][n] = (f32x4)0.f;

    int cached_tap = -1;
    int i00, i01, i10, i11;
    float w00, w01, w10, w11;

    auto ensure = [&](int kt) {
        cached_tap = kt;
        const int kd = kt / 3;
        const int dyk = kd - 1, dxk = kt - kd * 3 - 1;
        const size_t ob = ((size_t)(b * 18 + 2 * kt)) * HW_ + row * 64 + pl;
        const float ody = offset[ob];
        const float odx = offset[ob + HW_];
        const float py = (float)(row + dyk) + ody;
        const float px = (float)(pl + dxk) + odx;
        const float y0f = floorf(py), x0f = floorf(px);
        const float wy = py - y0f, wx = px - x0f;
        const int y0 = (int)y0f, x0 = (int)x0f;
        const float mm = mask[((size_t)(b * NK + kt)) * HW_ + row * 64 + pl];
        const float omy = 1.f - wy, omx = 1.f - wx;
        int iy, ix, iyc, ixc; bool v;
        iy = y0; ix = x0;
        v = (iy >= 0) & (iy < 64) & (ix >= 0) & (ix < 64);
        iyc = iy < 0 ? 0 : (iy > 63 ? 63 : iy); ixc = ix < 0 ? 0 : (ix > 63 ? 63 : ix);
        i00 = iyc * 64 + ixc; w00 = v ? omy * omx * mm : 0.f;
        iy = y0; ix = x0 + 1;
        v = (iy >= 0) & (iy < 64) & (ix >= 0) & (ix < 64);
        iyc = iy < 0 ? 0 : (iy > 63 ? 63 : iy); ixc = ix < 0 ? 0 : (ix > 63 ? 63 : ix);
        i01 = iyc * 64 + ixc; w01 = v ? omy * wx * mm : 0.f;
        iy = y0 + 1; ix = x0;
        v = (iy >= 0) & (iy < 64) & (ix >= 0) & (ix < 64);
        iyc = iy < 0 ? 0 : (iy > 63 ? 63 : iy); ixc = ix < 0 ? 0 : (ix > 63 ? 63 : ix);
        i10 = iyc * 64 + ixc; w10 = v ? wy * omx * mm : 0.f;
        iy = y0 + 1; ix = x0 + 1;
        v = (iy >= 0) & (iy < 64) & (ix >= 0) & (ix < 64);
        iyc = iy < 0 ? 0 : (iy > 63 ? 63 : iy); ixc = ix < 0 ? 0 : (ix > 63 ? 63 : ix);
        i11 = iyc * 64 + ixc; w11 = v ? wy * wx * mm : 0.f;
    };

    auto stage = [&](int buf, int s) {
        const int kt = s >> 3;
        if (kt != cached_tap) ensure(kt);
        const int cc = ((s & 7) << 5) + cs;                   // 4-channel base within K-chunk
        const unsigned short* xb = xTb + cc;
        u32x2 q00 = *reinterpret_cast<const u32x2*>(xb + (size_t)i00 * C_);
        u32x2 q01 = *reinterpret_cast<const u32x2*>(xb + (size_t)i01 * C_);
        u32x2 q10 = *reinterpret_cast<const u32x2*>(xb + (size_t)i10 * C_);
        u32x2 q11 = *reinterpret_cast<const u32x2*>(xb + (size_t)i11 * C_);
        unsigned short u[4];
        #pragma unroll
        for (int j = 0; j < 4; ++j) {
            const int word = j >> 1, sh = (j & 1) << 4;
            float v = fmaf(w00, bfu2f((unsigned short)(q00[word] >> sh)),
                      fmaf(w01, bfu2f((unsigned short)(q01[word] >> sh)),
                      fmaf(w10, bfu2f((unsigned short)(q10[word] >> sh)),
                           w11 * bfu2f((unsigned short)(q11[word] >> sh)))));
            u[j] = f2bf(v);
        }
        u32x2 pk;
        pk.x = (unsigned)u[0] | ((unsigned)u[1] << 16);
        pk.y = (unsigned)u[2] | ((unsigned)u[3] << 16);
        *reinterpret_cast<u32x2*>(&slds[buf][pl * 40 + cs]) = pk;   // 8B, aligned
    };

    auto compute = [&](int buf, int s) {
        const unsigned short* wpbase = wprep + (size_t)s * (CO_ * 32);
        s16x8 a[4];
        #pragma unroll
        for (int m = 0; m < 4; ++m) {
            const int o = wm * 64 + m * 16 + l15;
            a[m] = *reinterpret_cast<const s16x8*>(wpbase + o * 32 + g * 8);
        }
        #pragma unroll
        for (int n = 0; n < 2; ++n) {
            const int pr = wpn * 32 + n * 16 + l15;
            const s16x8 bb = *reinterpret_cast<const s16x8*>(&slds[buf][pr * 40 + g * 8]);
            #pragma unroll
            for (int m = 0; m < 4; ++m)
                acc[m][n] = __builtin_amdgcn_mfma_f32_16x16x32_bf16(a[m], bb, acc[m][n], 0, 0, 0);
        }
    };

    stage(0, 0);
    __syncthreads();
    for (int s = 0; s < NSTEP; ++s) {
        if (s + 1 < NSTEP) stage((s + 1) & 1, s + 1);
        compute(s & 1, s);
        __syncthreads();
    }

    // epilogue: D col = lane&15 (pixel), row = g*4 + r (o)
    #pragma unroll
    for (int m = 0; m < 4; ++m) {
        #pragma unroll
        for (int n = 0; n < 2; ++n) {
            const int o0 = wm * 64 + m * 16 + g * 4;
            const int pc = row * 64 + wpn * 32 + n * 16 + l15;
            #pragma unroll
            for (int r = 0; r < 4; ++r) {
                const int o = o0 + r;
                out[((size_t)(b * CO_ + o)) * HW_ + pc] = acc[m][n][r] + cb[o];
            }
        }
    }
}

// ================= fallback path (round-4 verified kernels, used if ws too small) =================
__global__ __launch_bounds__(256) void mask_kernel(
    const float* __restrict__ x, const float* __restrict__ dw,
    const float* __restrict__ pw, const float* __restrict__ pb,
    float* __restrict__ mask_out)
{
    __shared__ float hdn[C_ * 64];
    const int bid = blockIdx.x;
    const int b = bid >> 6, h = bid & 63;
    const int t = threadIdx.x;
    const int w = t & 63, cg = t >> 6;
    for (int c = cg * 64; c < cg * 64 + 64; ++c) {
        const float* xc = x + ((size_t)(b * C_ + c)) * HW_;
        const float* km = dw + c * 9;
        float s = 0.f;
        #pragma unroll
        for (int i = 0; i < 3; ++i) {
            int hh = h + i - 1;
            if (hh >= 0 && hh < 64) {
                const float* rr = xc + hh * 64;
                float lft = (w > 0)  ? rr[w - 1] : 0.f;
                float mid = rr[w];
                float rgt = (w < 63) ? rr[w + 1] : 0.f;
                s = fmaf(km[i*3+0], lft, s);
                s = fmaf(km[i*3+1], mid, s);
                s = fmaf(km[i*3+2], rgt, s);
            }
        }
        hdn[c * 64 + (w ^ (c & 31))] = fmaxf(s, 0.f);
    }
    __syncthreads();
    const int kk0 = cg * 3;
    for (int kk = kk0; kk < kk0 + 3; ++kk) {
        if (kk >= NK) break;
        float acc = pb[kk];
        const float* pwk = pw + kk * C_;
        for (int c = 0; c < C_; ++c)
            acc = fmaf(pwk[c], hdn[c * 64 + (w ^ (c & 31))], acc);
        mask_out[((size_t)(b * NK + kk)) * HW_ + h * 64 + w] = 1.f / (1.f + __expf(-acc));
    }
}

__global__ __launch_bounds__(512) void main_kernel(
    const float* __restrict__ x, const float* __restrict__ offset,
    const float* __restrict__ mask, const unsigned short* __restrict__ wprep,
    const float* __restrict__ cb, float* __restrict__ out)
{
    __shared__ short slds[2][64 * 40];
    const int bid = blockIdx.x;
    const int b = bid & 7;
    const int row = bid >> 3;
    const int t = threadIdx.x;
    const int pl = t & 63;
    const int csub = (t >> 6) << 2;
    const int lane = t & 63, wid = t >> 6;
    const int wm = wid >> 1, wpn = wid & 1;
    const int l15 = lane & 15, g = lane >> 4;
    f32x4 acc[4][2];
    #pragma unroll
    for (int m = 0; m < 4; ++m)
        #pragma unroll
        for (int n = 0; n < 2; ++n)
            acc[m][n] = (f32x4)0.f;
    int cached_tap = -1;
    int i00, i01, i10, i11;
    float w00, w01, w10, w11;
    auto ensure = [&](int kt) {
        cached_tap = kt;
        const int kd = kt / 3;
        const int dyk = kd - 1, dxk = kt - kd * 3 - 1;
        const size_t ob = ((size_t)(b * 18 + 2 * kt)) * HW_ + row * 64 + pl;
        const float ody = offset[ob];
        const float odx = offset[ob + HW_];
        const float py = (float)(row + dyk) + ody;
        const float px = (float)(pl + dxk) + odx;
        const float y0f = floorf(py), x0f = floorf(px);
        const float wy = py - y0f, wx = px - x0f;
        const int y0 = (int)y0f, x0 = (int)x0f;
        const float mm = mask[((size_t)(b * NK + kt)) * HW_ + row * 64 + pl];
        const float omy = 1.f - wy, omx = 1.f - wx;
        int iy, ix, iyc, ixc; bool v;
        iy = y0; ix = x0;
        v = (iy >= 0) & (iy < 64) & (ix >= 0) & (ix < 64);
        iyc = iy < 0 ? 0 : (iy > 63 ? 63 : iy); ixc = ix < 0 ? 0 : (ix > 63 ? 63 : ix);
        i00 = iyc * 64 + ixc; w00 = v ? omy * omx * mm : 0.f;
        iy = y0; ix = x0 + 1;
        v = (iy >= 0) & (iy < 64) & (ix >= 0) & (ix < 64);
        iyc = iy < 0 ? 0 : (iy > 63 ? 63 : iy); ixc = ix < 0 ? 0 : (ix > 63 ? 63 : ix);
        i01 = iyc * 64 + ixc; w01 = v ? omy * wx * mm : 0.f;
        iy = y0 + 1; ix = x0;
        v = (iy >= 0) & (iy < 64) & (ix >= 0) & (ix < 64);
        iyc = iy < 0 ? 0 : (iy > 63 ? 63 : iy); ixc = ix < 0 ? 0 : (ix > 63 ? 63 : ix);
        i10 = iyc * 64 + ixc; w10 = v ? wy * omx * mm : 0.f;
        iy = y0 + 1; ix = x0 + 1;
        v = (iy >= 0) & (iy < 64) & (ix >= 0) & (ix < 64);
        iyc = iy < 0 ? 0 : (iy > 63 ? 63 : iy); ixc = ix < 0 ? 0 : (ix > 63 ? 63 : ix);
        i11 = iyc * 64 + ixc; w11 = v ? wy * wx * mm : 0.f;
    };
    auto stage = [&](int buf, int s) {
        const int kt = s >> 3;
        if (kt != cached_tap) ensure(kt);
        const int cc = ((s & 7) << 5) + csub;
        const float* xb = x + ((size_t)(b * C_ + cc)) * HW_;
        unsigned short u[4];
        #pragma unroll
        for (int j = 0; j < 4; ++j) {
            const float* bp = xb + j * HW_;
            float v = fmaf(w00, bp[i00], fmaf(w01, bp[i01], fmaf(w10, bp[i10], w11 * bp[i11])));
            u[j] = f2bf(v);
        }
        u32x2 pk;
        pk.x = (unsigned)u[0] | ((unsigned)u[1] << 16);
        pk.y = (unsigned)u[2] | ((unsigned)u[3] << 16);
        *reinterpret_cast<u32x2*>(&slds[buf][pl * 40 + csub]) = pk;
    };
    auto compute = [&](int buf, int s) {
        const unsigned short* wpbase = wprep + (size_t)s * (CO_ * 32);
        s16x8 a[4];
        #pragma unroll
        for (int m = 0; m < 4; ++m) {
            const int o = wm * 64 + m * 16 + l15;
            a[m] = *reinterpret_cast<const s16x8*>(wpbase + o * 32 + g * 8);
        }
        #pragma unroll
        for (int n = 0; n < 2; ++n) {
            const int pr = wpn * 32 + n * 16 + l15;
            const s16x8 bb = *reinterpret_cast<const s16x8*>(&slds[buf][pr * 40 + g * 8]);
            #pragma unroll
            for (int m = 0; m < 4; ++m)
                acc[m][n] = __builtin_amdgcn_mfma_f32_16x16x32_bf16(a[m], bb, acc[m][n], 0, 0, 0);
        }
    };
    stage(0, 0);
    __syncthreads();
    for (int s = 0; s < NSTEP; ++s) {
        if (s + 1 < NSTEP) stage((s + 1) & 1, s + 1);
        compute(s & 1, s);
        __syncthreads();
    }
    #pragma unroll
    for (int m = 0; m < 4; ++m) {
        #pragma unroll
        for (int n = 0; n < 2; ++n) {
            const int o0 = wm * 64 + m * 16 + g * 4;
            const int pc = row * 64 + wpn * 32 + n * 16 + l15;
            #pragma unroll
            for (int r = 0; r < 4; ++r) {
                const int o = o0 + r;
                out[((size_t)(b * CO_ + o)) * HW_ + pc] = acc[m][n][r] + cb[o];
            }
        }
    }
}

extern "C" void kernel_launch(void* const* d_in, const int* in_sizes, int n_in,
                              void* d_out, int out_size, void* d_ws, size_t ws_size,
                              hipStream_t stream) {
    const float* x      = (const float*)d_in[0];
    const float* offset = (const float*)d_in[1];
    const float* dw     = (const float*)d_in[2];
    const float* pw     = (const float*)d_in[3];
    const float* pb     = (const float*)d_in[4];
    const float* cw     = (const float*)d_in[5];
    const float* cb     = (const float*)d_in[6];
    float* out = (float*)d_out;

    const size_t XT_BYTES   = (size_t)B_ * HW_ * C_ * 2;          // 16 MB
    const size_t MASK_BYTES = (size_t)B_ * NK * HW_ * 4;          // 1.18 MB
    const size_t WP_BYTES   = (size_t)NSTEP * CO_ * 32 * 2;       // 1.18 MB

    if (ws_size >= XT_BYTES + MASK_BYTES + WP_BYTES) {
        unsigned short* xT = (unsigned short*)d_ws;
        float* mask_ws = (float*)((char*)d_ws + XT_BYTES);
        unsigned short* wprep = (unsigned short*)((char*)d_ws + XT_BYTES + MASK_BYTES);
        tr_kernel<<<B_ * 64, 256, 0, stream>>>(x, xT);
        mask2_kernel<<<B_ * 64, 512, 0, stream>>>(xT, dw, pw, pb, mask_ws);
        wprep_kernel<<<(NSTEP * CO_ * 32) / 256, 256, 0, stream>>>(cw, wprep);
        main5_kernel<<<512, 512, 0, stream>>>(xT, offset, mask_ws, wprep, cb, out);
    } else {
        float* mask_ws = (float*)d_ws;
        unsigned short* wprep = (unsigned short*)((char*)d_ws + MASK_BYTES);
        mask_kernel<<<B_ * 64, 256, 0, stream>>>(x, dw, pw, pb, mask_ws);
        wprep_kernel<<<(NSTEP * CO_ * 32) / 256, 256, 0, stream>>>(cw, wprep);
        main_kernel<<<512, 512, 0, stream>>>(x, offset, mask_ws, wprep, cb, out);
    }
}